// Round 3
// baseline (206.641 us; speedup 1.0000x reference)
//
#include <hip/hip_runtime.h>
#include <math.h>

#define BN    32
#define CN    256
#define HN    56
#define WN    56
#define HWN   (HN * WN)          // 3136
#define CHWN  (CN * HWN)         // 802816
#define NPOS  (BN * HWN)         // 100352
#define NTOT  (BN * CHWN)        // 25690112
#define KCH   8                  // channel chunks
#define CPK   (CN / KCH)         // 32 channels per chunk
#define PBLK  (NPOS / 256)       // 392 blocks per chunk slice

typedef float fx4 __attribute__((ext_vector_type(4)));

// Kernel 1: partial channel reduction. Thread = (chunk k, position p),
// reduces 32 channels. 3136 blocks -> ~49 waves/CU, latency fully hidden.
__global__ void sa_reduce_part_kernel(const float* __restrict__ x,
                                      float* __restrict__ psum,
                                      float* __restrict__ pmax) {
    int k = blockIdx.x / PBLK;                   // 0..7
    int pb = blockIdx.x - k * PBLK;
    int p = pb * 256 + threadIdx.x;              // 0..NPOS-1
    int b = p / HWN;
    int s = p - b * HWN;
    const float* xp = x + (size_t)b * CHWN + (size_t)(k * CPK) * HWN + s;
    float sum = 0.0f;
    float m = -INFINITY;
#pragma unroll
    for (int c = 0; c < CPK; ++c) {
        float v = xp[(size_t)c * HWN];
        sum += v;
        m = fmaxf(m, v);
    }
    psum[k * NPOS + p] = sum;
    pmax[k * NPOS + p] = m;
}

// Kernel 2: fold the 8 partials into avg/max maps.
__global__ void sa_combine_kernel(const float* __restrict__ psum,
                                  const float* __restrict__ pmax,
                                  float* __restrict__ avg,
                                  float* __restrict__ mx) {
    int p = blockIdx.x * blockDim.x + threadIdx.x;
    if (p >= NPOS) return;
    float sum = 0.0f;
    float m = -INFINITY;
#pragma unroll
    for (int k = 0; k < KCH; ++k) {
        sum += psum[k * NPOS + p];
        m = fmaxf(m, pmax[k * NPOS + p]);
    }
    avg[p] = sum * (1.0f / (float)CN);
    mx[p] = m;
}

// Kernel 3: 7x7 conv over the 2-channel (avg,max) map + sigmoid -> att map.
__global__ void sa_conv_kernel(const float* __restrict__ avg,
                               const float* __restrict__ mx,
                               const float* __restrict__ cw,
                               float* __restrict__ att) {
    int p = blockIdx.x * blockDim.x + threadIdx.x;
    if (p >= NPOS) return;
    int b = p / HWN;
    int s = p - b * HWN;
    int h = s / WN;
    int w = s - h * WN;
    const float* a0 = avg + b * HWN;
    const float* m0 = mx + b * HWN;
    float acc = 0.0f;
#pragma unroll
    for (int kh = 0; kh < 7; ++kh) {
        int hh = h + kh - 3;
        if (hh < 0 || hh >= HN) continue;
#pragma unroll
        for (int kw = 0; kw < 7; ++kw) {
            int ww = w + kw - 3;
            if (ww < 0 || ww >= WN) continue;
            int idx = hh * WN + ww;
            acc = fmaf(cw[kh * 7 + kw],      a0[idx], acc);
            acc = fmaf(cw[49 + kh * 7 + kw], m0[idx], acc);
        }
    }
    att[p] = 1.0f / (1.0f + expf(-acc));
}

// Kernel 4: out = x * att (broadcast over channels), fx4 vectorized.
// Grid: (CHWN/4/256, BN). att reads are L1/L2-resident (12.5 KB per b).
__global__ void sa_mul_kernel(const fx4* __restrict__ x4,
                              const float* __restrict__ att,
                              fx4* __restrict__ out4) {
    int b = blockIdx.y;
    int i = blockIdx.x * blockDim.x + threadIdx.x;   // fx4 idx within b
    int e = i * 4;                                   // element within b-plane
    int s = e % HWN;                                 // spatial pos (mult of 4)
    const fx4 a = *(const fx4*)(att + b * HWN + s);
    size_t gi = (size_t)b * (CHWN / 4) + i;
    fx4 v = x4[gi];
    v *= a;
    __builtin_nontemporal_store(v, &out4[gi]);
}

extern "C" void kernel_launch(void* const* d_in, const int* in_sizes, int n_in,
                              void* d_out, int out_size, void* d_ws, size_t ws_size,
                              hipStream_t stream) {
    const float* x  = (const float*)d_in[0];
    const float* cw = (const float*)d_in[1];
    float* out = (float*)d_out;

    float* psum = (float*)d_ws;            // KCH*NPOS
    float* pmax = psum + KCH * NPOS;       // KCH*NPOS
    float* avg  = pmax + KCH * NPOS;       // NPOS
    float* mx   = avg + NPOS;              // NPOS
    float* att  = mx + NPOS;               // NPOS

    sa_reduce_part_kernel<<<KCH * PBLK, 256, 0, stream>>>(x, psum, pmax);
    sa_combine_kernel<<<PBLK, 256, 0, stream>>>(psum, pmax, avg, mx);
    sa_conv_kernel<<<PBLK, 256, 0, stream>>>(avg, mx, cw, att);

    dim3 mgrid(CHWN / 4 / 256, BN);        // (784, 32)
    sa_mul_kernel<<<mgrid, 256, 0, stream>>>((const fx4*)x, att, (fx4*)out);
}